// Round 1
// baseline (402.753 us; speedup 1.0000x reference)
//
#include <hip/hip_runtime.h>
#include <cstdint>
#include <cstddef>

// Problem constants (B=8, H=W=1024)
#define N_PIX   1048576
#define B_ROWS  8
#define K_ALL   524288          // max(1, int(N*0.5))
#define WG_PER_ROW 256          // blocks per row
#define ITERS   4               // quads per thread: (N_PIX/4)/WG_PER_ROW/256
#define NBINS   1024            // float bits >> 22 (sign=0, 8 exp, 1 mantissa bit)
#define BSHIFT  22
#define CSHIFT  40              // u64 = (count << 40) | fixed_sum(2^-18)
#define SUMMASK ((1ull << CSHIFT) - 1ull)
#define FPSCALE 262144.0f       // 2^18

// Packing margins (verified): per-row per-bin count <= ~57K < 2^24;
// per-row per-bin fixed sum <= ~2.1e10 < 2^40. Per-block values far smaller.
// Selection: suffix-scan count hist for threshold bin T1; bins > T1 summed
// exactly; partial bin via shifted-uniform model (exact at Kp == cntT1).
// 1024 bins previously verified absmax 0.0 (R6 journal note).
//
// Fused single kernel: last block per row (threadfence + rowCnt counter, the
// rocPRIM decoupled-completion pattern) performs the selection; globally-last
// row writes the final mean. Cross-XCD visibility: producers use device-scope
// atomics; consumers re-read shared state via atomic RMWs (returns old value)
// after an acquire __threadfence().

__global__ __launch_bounds__(256, 6) void k_fused(
    const float4* __restrict__ lg, const int4* __restrict__ tg, const int4* __restrict__ mk,
    unsigned long long* __restrict__ hist,
    unsigned* __restrict__ rowNpos, double* __restrict__ rowSpos,
    unsigned* __restrict__ rowCnt, unsigned* __restrict__ doneCnt,
    double* __restrict__ rowPer, float* __restrict__ out)
{
    __shared__ unsigned long long hq[NBINS];   // 8 KB
    __shared__ unsigned swp[4];
    __shared__ double   sws[4];
    __shared__ unsigned sc[2][256];
    __shared__ double   sd[2][256];
    __shared__ int rT; __shared__ unsigned rcntgt; __shared__ double rsumgt;
    __shared__ int isLast;

    const int tid = threadIdx.x;
    for (int b = tid; b < NBINS; b += 256) hq[b] = 0ull;

    const int r = blockIdx.x >> 8;                          // WG_PER_ROW == 256
    const size_t base = (size_t)blockIdx.x * (ITERS * 256) + tid;

    float4 x[ITERS]; int4 t[ITERS]; int4 m[ITERS];
    #pragma unroll
    for (int i = 0; i < ITERS; ++i) {
        x[i] = lg[base + (size_t)i * 256];
        t[i] = tg[base + (size_t)i * 256];
        m[i] = mk[base + (size_t)i * 256];
    }
    __syncthreads();   // LDS init visible

    unsigned npos = 0; float spos = 0.f;

    auto proc = [&](float xx, int tt, int mm) {
        float ax = fabsf(xx);
        float e = __expf(-ax);
        float l = __logf(1.f + e);
        float bce = fmaxf(xx, 0.f) - xx * (float)tt + l;
        if (mm) {
            if (tt) { npos++; spos += bce; }
            else {
                unsigned bin = __float_as_uint(bce) >> BSHIFT;
                if (bin >= NBINS) bin = NBINS - 1;          // never hit for this data
                unsigned fx = (unsigned)__float2uint_rn(bce * FPSCALE);
                atomicAdd(&hq[bin], (1ull << CSHIFT) | (unsigned long long)fx);
            }
        }
    };

    #pragma unroll
    for (int i = 0; i < ITERS; ++i) {
        proc(x[i].x, t[i].x, m[i].x);
        proc(x[i].y, t[i].y, m[i].y);
        proc(x[i].z, t[i].z, m[i].z);
        proc(x[i].w, t[i].w, m[i].w);
    }

    // block-level reduce of npos/sumPos
    for (int o = 32; o; o >>= 1) {
        npos += __shfl_down(npos, o);
        spos += __shfl_down(spos, o);
    }
    if ((tid & 63) == 0) { swp[tid >> 6] = npos; sws[tid >> 6] = (double)spos; }
    __syncthreads();   // also makes all hq atomics visible for the flush below
    if (tid == 0) {
        unsigned bn = swp[0] + swp[1] + swp[2] + swp[3];
        double   bs = sws[0] + sws[1] + sws[2] + sws[3];
        if (bn) atomicAdd(&rowNpos[r], bn);
        if (bs != 0.0) atomicAdd(&rowSpos[r], bs);
    }

    // flush nonzero bins -> global row hist
    unsigned long long* gh = hist + (size_t)r * NBINS;
    for (int b = tid; b < NBINS; b += 256) {
        unsigned long long v = hq[b];
        if (v) atomicAdd(&gh[b], v);
    }

    // completion counter: last block of this row does the selection
    __threadfence();
    if (tid == 0) isLast = (atomicAdd(&rowCnt[r], 1u) == WG_PER_ROW - 1);
    __syncthreads();
    if (!isLast) return;
    __threadfence();   // acquire

    // ---------- per-row selection (one block per row reaches here) ----------
    const double inv = 1.0 / (double)FPSCALE;

    // re-read row totals coherently (atomic RMW returns current value)
    if (tid == 0) {
        swp[0] = atomicAdd(&rowNpos[r], 0u);
        sws[0] = atomicAdd(&rowSpos[r], 0.0);
    }
    __syncthreads();
    const unsigned nposR = swp[0];
    const double  sumPos = sws[0];

    // per-thread chunk of 4 bins, scanned high->low; coherent atomic reads
    const int per = NBINS / 256;                 // 4
    const int b0 = NBINS - 1 - tid * per;
    unsigned lc[4]; double lsum[4];
    unsigned pc = 0; double ps = 0.0;
    #pragma unroll
    for (int i = 0; i < per; ++i) {
        unsigned long long v = atomicOr(&gh[b0 - i], 0ull);
        lc[i] = (unsigned)(v >> CSHIFT);
        lsum[i] = (double)(v & SUMMASK) * inv;
        pc += lc[i]; ps += lsum[i];
    }

    // inclusive Hillis-Steele scan (thread t covers bins >= NBINS - per*(t+1))
    int pp = 0;
    sc[0][tid] = pc; sd[0][tid] = ps;
    __syncthreads();
    for (int ofs = 1; ofs < 256; ofs <<= 1) {
        unsigned c = sc[pp][tid]; double s = sd[pp][tid];
        if (tid >= ofs) { c += sc[pp][tid - ofs]; s += sd[pp][tid - ofs]; }
        sc[pp ^ 1][tid] = c; sd[pp ^ 1][tid] = s;
        pp ^= 1;
        __syncthreads();
    }
    const unsigned nneg   = sc[pp][255];
    const double   sumNeg = sd[pp][255];

    long kl = (long)K_ALL - (long)nposR;
    if (kl < 0) kl = 0;
    if (kl > (long)nneg) kl = (long)nneg;
    const unsigned Kneg = (unsigned)kl;

    double sum_sel = 0.0;
    if (Kneg >= nneg) {
        sum_sel = sumNeg;                        // keep-all (or Kneg==nneg==0)
    } else if (Kneg > 0) {
        // threshold bin: exactly one thread has exc < Kneg <= inc
        unsigned inc = sc[pp][tid];
        unsigned exc = inc - pc;
        double   exs = sd[pp][tid] - ps;
        if (exc < Kneg && Kneg <= inc) {
            unsigned cum = exc; double csum = exs;
            #pragma unroll
            for (int i = 0; i < per; ++i) {
                if (cum + lc[i] >= Kneg) { rT = b0 - i; rcntgt = cum; rsumgt = csum; break; }
                cum += lc[i]; csum += lsum[i];
            }
        }
        __syncthreads();
        if (tid == 0) {
            const int T1 = rT;
            unsigned long long v = atomicOr(&gh[T1], 0ull);
            const unsigned cntT1 = (unsigned)(v >> CSHIFT);
            const double   sumT1 = (double)(v & SUMMASK) * inv;
            const unsigned Kp = Kneg - rcntgt;   // 1..cntT1
            const float lo = __uint_as_float((unsigned)T1 << BSHIFT);
            const float hi = __uint_as_float((unsigned)(T1 + 1) << BSHIFT);
            const double w = (double)hi - (double)lo;
            const double avg = sumT1 / (double)cntT1;
            // shifted-uniform top-Kp mean; exact when Kp == cntT1
            const double topmean = avg + 0.5 * w * (1.0 - (double)Kp / (double)cntT1);
            sum_sel = rsumgt + (double)Kp * topmean;
        }
    }

    if (tid == 0) {
        unsigned long long kk = (unsigned long long)nposR + (unsigned long long)Kneg;
        double per_s = 0.0;
        if (kk > 0) per_s = (sumPos + sum_sel) / (double)kk;
        // kk==0 => no tissue => reference falls back to loss[:,0] == 0
        rowPer[r] = per_s;
        __threadfence();
        if (atomicAdd(doneCnt, 1u) == B_ROWS - 1) {
            __threadfence();   // acquire
            double s = 0.0;
            #pragma unroll
            for (int i = 0; i < B_ROWS; ++i) s += atomicAdd(&rowPer[i], 0.0);
            *out = (float)(s / (double)B_ROWS);
        }
    }
}

// ---------- launch ----------
extern "C" void kernel_launch(void* const* d_in, const int* in_sizes, int n_in,
                              void* d_out, int out_size, void* d_ws, size_t ws_size,
                              hipStream_t stream)
{
    const float* logits = (const float*)d_in[0];
    const int*   targets = (const int*)d_in[1];
    const int*   tissue = (const int*)d_in[2];

    char* ws = (char*)d_ws;
    size_t off = 0;
    unsigned long long* hist = (unsigned long long*)(ws + off);
    off += (size_t)B_ROWS * NBINS * 8;                      // 64 KB
    double*   rowSpos = (double*)(ws + off);   off += B_ROWS * 8;
    double*   rowPer  = (double*)(ws + off);   off += B_ROWS * 8;
    unsigned* rowNpos = (unsigned*)(ws + off); off += B_ROWS * 4;
    unsigned* rowCnt  = (unsigned*)(ws + off); off += B_ROWS * 4;
    unsigned* doneCnt = (unsigned*)(ws + off); off += 4;

    hipMemsetAsync(ws, 0, off, stream);

    const int NBLK = B_ROWS * WG_PER_ROW;   // 2048
    k_fused<<<NBLK, 256, 0, stream>>>(
        (const float4*)logits, (const int4*)targets, (const int4*)tissue,
        hist, rowNpos, rowSpos, rowCnt, doneCnt, rowPer, (float*)d_out);
}

// Round 2
// 124.897 us; speedup vs baseline: 3.2247x; 3.2247x over previous
//
#include <hip/hip_runtime.h>
#include <cstdint>
#include <cstddef>

// Problem constants (B=8, H=W=1024)
#define N_PIX   1048576
#define B_ROWS  8
#define K_ALL   524288          // max(1, int(N*0.5))
#define WG_PER_ROW 256          // pass1 blocks per row
#define ITERS   4               // quads per thread: (N_PIX/4)/WG_PER_ROW/256
#define NBINS   1024            // LINEAR bins on [0,8), width 1/128
#define BSCALE  128.0f          // bins per unit loss
#define CSHIFT  42              // u64 = (count << 42) | fixed_sum(2^-18)
#define SUMMASK ((1ull << CSHIFT) - 1ull)
#define FPSCALE 262144.0f       // 2^18 fixed-point scale for packed sums

// Linear binning rationale (R2): float-bit binning put ~5% of negatives in one
// bin near the softplus mode (width 1/16 at 0.69) -> 8-16-way same-address
// ds_atomic_add_u64 serialization (atomics serialize per lane, unlike reads).
// Linear width-1/128 bins cut hot-bin mass to ~0.6% -> ~2-way (free).
// Accuracy: bins are FINER than before near the mode; threshold-bin
// interpolation error ~1e-5 << 1.6e-2 tolerance.
// Packing margins: per-row bin count <= ~3.3K << 2^22; per-row bin fixed sum
// <= 8*2^18*524288 = 1.1e12 < 2^42 even in the all-one-bin pathological case.
//
// R1 lesson (reverted): single-kernel fusion needs __threadfence() for
// cross-XCD visibility; on gfx950 that is buffer_wbl2/buffer_inv (full L2
// writeback/invalidate) per block -> 8x slowdown. Kernel boundary is the
// cheap coherence mechanism; keep two dispatches.

// ---------- K1: loss + packed count/sum LDS hist + per-block npos/sumPos ----------
__global__ __launch_bounds__(256, 6) void k_pass1(
    const float4* __restrict__ lg, const int4* __restrict__ tg, const int4* __restrict__ mk,
    unsigned long long* __restrict__ hist,
    unsigned* __restrict__ partNpos, double* __restrict__ partSpos, float* __restrict__ out)
{
    __shared__ unsigned long long hq[NBINS];   // 8 KB
    __shared__ unsigned swp[4];
    __shared__ double   sws[4];
    const int tid = threadIdx.x;
    for (int b = tid; b < NBINS; b += 256) hq[b] = 0ull;
    if (blockIdx.x == 0 && tid == 0) *out = 0.f;   // k_final (later dispatch) accumulates

    const int r = blockIdx.x >> 8;                          // WG_PER_ROW == 256
    const size_t base = (size_t)blockIdx.x * (ITERS * 256) + tid;

    float4 x[ITERS]; int4 t[ITERS]; int4 m[ITERS];
    #pragma unroll
    for (int i = 0; i < ITERS; ++i) {
        x[i] = lg[base + (size_t)i * 256];
        t[i] = tg[base + (size_t)i * 256];
        m[i] = mk[base + (size_t)i * 256];
    }
    __syncthreads();   // LDS init visible

    unsigned npos = 0; float spos = 0.f;

    auto proc = [&](float xx, int tt, int mm) {
        float ax = fabsf(xx);
        float e = __expf(-ax);
        float l = __logf(1.f + e);
        float bce = fmaxf(xx, 0.f) - xx * (float)tt + l;
        if (mm) {
            if (tt) { npos++; spos += bce; }
            else {
                unsigned bin = __float2uint_rz(bce * BSCALE);   // HW cvt clamps
                if (bin >= NBINS) bin = NBINS - 1;              // tail guard
                unsigned fx = (unsigned)__float2uint_rn(bce * FPSCALE);
                atomicAdd(&hq[bin], (1ull << CSHIFT) | (unsigned long long)fx);
            }
        }
    };

    #pragma unroll
    for (int i = 0; i < ITERS; ++i) {
        proc(x[i].x, t[i].x, m[i].x);
        proc(x[i].y, t[i].y, m[i].y);
        proc(x[i].z, t[i].z, m[i].z);
        proc(x[i].w, t[i].w, m[i].w);
    }

    // block-level reduce of npos/sumPos -> per-block partials
    for (int o = 32; o; o >>= 1) {
        npos += __shfl_down(npos, o);
        spos += __shfl_down(spos, o);
    }
    if ((tid & 63) == 0) { swp[tid >> 6] = npos; sws[tid >> 6] = (double)spos; }
    __syncthreads();
    if (tid == 0) {
        partNpos[blockIdx.x] = swp[0] + swp[1] + swp[2] + swp[3];
        partSpos[blockIdx.x] = sws[0] + sws[1] + sws[2] + sws[3];
    }

    // flush nonzero bins -> global row hist (one u64 atomic per occupied bin)
    unsigned long long* gh = hist + (size_t)r * NBINS;
    for (int b = tid; b < NBINS; b += 256) {
        unsigned long long v = hq[b];
        if (v) atomicAdd(&gh[b], v);
    }
}

// ---------- K2: per-row selection from packed hist + output ----------
__global__ __launch_bounds__(256) void k_final(
    const unsigned long long* __restrict__ hist,
    const unsigned* __restrict__ partNpos, const double* __restrict__ partSpos,
    float* __restrict__ out)
{
    __shared__ unsigned sc[2][256];
    __shared__ double   sd[2][256];
    __shared__ unsigned swp[4];
    __shared__ double   sws[4];
    __shared__ int rT; __shared__ unsigned rcntgt; __shared__ double rsumgt;

    const int r = blockIdx.x, tid = threadIdx.x;
    const unsigned long long* gh = hist + (size_t)r * NBINS;
    const double inv = 1.0 / (double)FPSCALE;

    // reduce per-block partials (WG_PER_ROW == 256 entries)
    {
        unsigned np = partNpos[r * 256 + tid];
        double   sp = partSpos[r * 256 + tid];
        for (int o = 32; o; o >>= 1) { np += __shfl_down(np, o); sp += __shfl_down(sp, o); }
        if ((tid & 63) == 0) { swp[tid >> 6] = np; sws[tid >> 6] = sp; }
    }
    __syncthreads();
    const unsigned npos = swp[0] + swp[1] + swp[2] + swp[3];
    const double sumPos = sws[0] + sws[1] + sws[2] + sws[3];
    __syncthreads();

    // per-thread chunk of 4 bins, scanned high->low; cache unpacked values
    const int per = NBINS / 256;                 // 4
    const int b0 = NBINS - 1 - tid * per;
    unsigned lc[4]; double lsum[4];
    unsigned pc = 0; double ps = 0.0;
    #pragma unroll
    for (int i = 0; i < per; ++i) {
        unsigned long long v = gh[b0 - i];
        lc[i] = (unsigned)(v >> CSHIFT);
        lsum[i] = (double)(v & SUMMASK) * inv;
        pc += lc[i]; ps += lsum[i];
    }

    // inclusive Hillis-Steele scan (thread t covers bins >= NBINS - per*(t+1))
    int pp = 0;
    sc[0][tid] = pc; sd[0][tid] = ps;
    __syncthreads();
    for (int ofs = 1; ofs < 256; ofs <<= 1) {
        unsigned c = sc[pp][tid]; double s = sd[pp][tid];
        if (tid >= ofs) { c += sc[pp][tid - ofs]; s += sd[pp][tid - ofs]; }
        sc[pp ^ 1][tid] = c; sd[pp ^ 1][tid] = s;
        pp ^= 1;
        __syncthreads();
    }
    const unsigned nneg   = sc[pp][255];
    const double   sumNeg = sd[pp][255];

    long kl = (long)K_ALL - (long)npos;
    if (kl < 0) kl = 0;
    if (kl > (long)nneg) kl = (long)nneg;
    const unsigned Kneg = (unsigned)kl;

    double sum_sel = 0.0;
    if (Kneg >= nneg) {
        sum_sel = sumNeg;                        // keep-all (or Kneg==nneg==0)
    } else if (Kneg > 0) {
        // threshold bin: exactly one thread has exc < Kneg <= inc
        unsigned inc = sc[pp][tid];
        unsigned exc = inc - pc;
        double   exs = sd[pp][tid] - ps;
        if (exc < Kneg && Kneg <= inc) {
            unsigned cum = exc; double csum = exs;
            #pragma unroll
            for (int i = 0; i < per; ++i) {
                if (cum + lc[i] >= Kneg) { rT = b0 - i; rcntgt = cum; rsumgt = csum; break; }
                cum += lc[i]; csum += lsum[i];
            }
        }
        __syncthreads();
        if (tid == 0) {
            const int T1 = rT;
            unsigned long long v = gh[T1];
            const unsigned cntT1 = (unsigned)(v >> CSHIFT);
            const double   sumT1 = (double)(v & SUMMASK) * inv;
            const unsigned Kp = Kneg - rcntgt;   // 1..cntT1
            const double lo = (double)T1 / (double)BSCALE;
            const double hi = (double)(T1 + 1) / (double)BSCALE;
            const double w = hi - lo;            // 1/128
            const double avg = sumT1 / (double)cntT1;
            // shifted-uniform top-Kp mean; exact when Kp == cntT1
            const double topmean = avg + 0.5 * w * (1.0 - (double)Kp / (double)cntT1);
            sum_sel = rsumgt + (double)Kp * topmean;
        }
    }

    if (tid == 0) {
        unsigned long long kk = (unsigned long long)npos + (unsigned long long)Kneg;
        double per_s = 0.0;
        if (kk > 0) per_s = (sumPos + sum_sel) / (double)kk;
        // kk==0 => no tissue => reference falls back to loss[:,0] == 0
        atomicAdd(out, (float)(per_s / (double)B_ROWS));
    }
}

// ---------- launch ----------
extern "C" void kernel_launch(void* const* d_in, const int* in_sizes, int n_in,
                              void* d_out, int out_size, void* d_ws, size_t ws_size,
                              hipStream_t stream)
{
    const float* logits = (const float*)d_in[0];
    const int*   targets = (const int*)d_in[1];
    const int*   tissue = (const int*)d_in[2];

    const int NBLK = B_ROWS * WG_PER_ROW;   // 2048
    char* ws = (char*)d_ws;
    size_t off = 0;
    // zeroed region: packed hist (at ws start)
    unsigned long long* hist = (unsigned long long*)(ws + off);
    off += (size_t)B_ROWS * NBINS * 8;      // 64 KB
    size_t zero_size = off;
    // non-zeroed partials (every slot written before read)
    unsigned* partNpos = (unsigned*)(ws + off); off += (size_t)NBLK * 4;
    double*   partSpos = (double*)(ws + off);   off += (size_t)NBLK * 8;

    hipMemsetAsync(ws, 0, zero_size, stream);

    k_pass1<<<NBLK, 256, 0, stream>>>(
        (const float4*)logits, (const int4*)targets, (const int4*)tissue,
        hist, partNpos, partSpos, (float*)d_out);
    k_final<<<B_ROWS, 256, 0, stream>>>(hist, partNpos, partSpos, (float*)d_out);
}